// Round 16
// baseline (271.937 us; speedup 1.0000x reference)
//
#include <hip/hip_runtime.h>

#define NROWS  16384
#define NCODES 16384
#define DIM    256
#define CAP    15          // two-pass fallback candidates/row (r8-proven)
#define CAP2   96          // seeded path candidates/row (r10-proven)

typedef __attribute__((ext_vector_type(8))) _Float16 v8h;   // fp16x8 MFMA operand
typedef __attribute__((ext_vector_type(4))) float    f32x4; // MFMA 16x16 accum

// ---------------- two-pass fallback ws layout (r3-r8 proven: 34,734,336) -------
#define WS_ZT      0ULL
#define WS_ZHF     16777216ULL
#define WS_CHF     25165824ULL
#define WS_ZS      33554432ULL
#define WS_DOTMAX  33619968ULL
#define WS_CNT     33685504ULL
#define WS_CAND    33751040ULL
#define WS_SCAL    34734080ULL
#define WS_NEEDED  34734336ULL

// ---------------- seeded-path ws layout (40,042,752; granted r9-r15) -----------
#define NWS_ZT      0ULL          // float    z_t[16384][256]        16 MB
#define NWS_ZHF     16777216ULL   // _Float16 z frags                 8 MB
#define NWS_CHF     25165824ULL   // _Float16 cb frags (x 2^14)       8 MB
#define NWS_ZS      33554432ULL   // float    zs32[16384]            64 KB
#define NWS_DOTMAX  33619968ULL   // uint     dotmax key[16384]      64 KB
#define NWS_CNT     33685504ULL   // uint     cnt[16384]             64 KB
#define NWS_SCAL    33751040ULL   // uint     [0]=zsmax [1]=esmax [2]=M'  256 B
#define NWS_CAND    33751296ULL   // uint     cand[16384][CAP2]       6 MB
#define NWS_NEEDED  40042752ULL

__device__ inline unsigned fkey(float f) {
    unsigned u = __float_as_uint(f);
    return (u & 0x80000000u) ? ~u : (u | 0x80000000u);
}
__device__ inline float fdec(unsigned k) {
    unsigned u = (k & 0x80000000u) ? (k ^ 0x80000000u) : ~k;
    return __uint_as_float(u);
}
// Screening margin in SCALED dot units (dot' = dot * 2^14); r4-r14-proven
// formula. Computed ONLY in the tiny vq_margin kernel (r12/r13 lesson:
// inlining costs 8 VGPR -> crosses 64-granule -> -33% collect).
__device__ inline float margin_from(const unsigned* scal) {
    float zsM = fdec(scal[0]) * 1.0001f;
    float esM = fdec(scal[1]) * 1.0001f;
    float delta = 1.1e-3f * sqrtf(zsM * esM) + 2e-6f;
    return 16384.0f * (1.25f * (2.0f * delta + 3.2e-5f));
}
// async 16B global->LDS (gfx950); vmcnt-tracked, LDS dest = wave base + lane*16
__device__ inline void gll16(const void* g, void* s) {
    __builtin_amdgcn_global_load_lds(
        (const __attribute__((address_space(1))) unsigned int*)g,
        (__attribute__((address_space(3))) unsigned int*)s, 16, 0, 0);
}

// ===========================================================================
// MERGED prep (r14-proven): blocks 0-255 = prep_z body (zs32 numpy-pairwise +
// zt transpose + fused f16 pack + scal[0]); blocks 256-511 = prep_cb body.
// NOTE (r15 lesson): every wave of seed/collect must scan ALL chunks of its
// strip for its own rows — the collect barriers implement cross-wave tile
// sharing; partitioning chunks across waves leaves 3/4 of columns untested.
__global__ void vq_prep(const float* __restrict__ z, float* __restrict__ zt,
                        float* __restrict__ zs, _Float16* __restrict__ zhf,
                        const float* __restrict__ cb, _Float16* __restrict__ chf,
                        unsigned* __restrict__ scal) {
    if (blockIdx.x < 256) {
        int n = blockIdx.x * 64 + threadIdx.x;
        int b = n >> 10, hw = n & 1023;
        const float* p = z + (size_t)b * (DIM * 1024) + hw;
        float* zrow = zt + (size_t)n * DIM;
        const size_t fragbase = (size_t)((n >> 4) * 8) * 64 + (n & 15);
        float h[2];
        #pragma unroll
        for (int half = 0; half < 2; ++half) {
            const float* q = p + (size_t)(half * 128) * 1024;
            float* qr = zrow + half * 128;
            float r[8];
            v8h val;
            #pragma unroll
            for (int j = 0; j < 8; ++j) {
                float v = q[(size_t)j * 1024];
                qr[j] = v;
                r[j] = __fmul_rn(v, v);
                val[j] = (_Float16)v;
            }
            *(v8h*)(zhf + (fragbase + (size_t)(half * 4) * 64) * 8) = val;
            for (int i = 8; i < 128; i += 8) {
                #pragma unroll
                for (int j = 0; j < 8; ++j) {
                    float v = q[(size_t)(i + j) * 1024];
                    qr[i + j] = v;
                    r[j] = __fadd_rn(r[j], __fmul_rn(v, v));
                    val[j] = (_Float16)v;
                }
                int ks = half * 4 + (i >> 5), qq = (i >> 3) & 3;
                *(v8h*)(zhf + (fragbase + (size_t)ks * 64 + qq * 16) * 8) = val;
            }
            float s01 = __fadd_rn(r[0], r[1]), s23 = __fadd_rn(r[2], r[3]);
            float s45 = __fadd_rn(r[4], r[5]), s67 = __fadd_rn(r[6], r[7]);
            h[half] = __fadd_rn(__fadd_rn(s01, s23), __fadd_rn(s45, s67));
        }
        float total = __fadd_rn(h[0], h[1]);
        zs[n] = total;
        float w = total;
        #pragma unroll
        for (int off = 1; off < 64; off <<= 1) w = fmaxf(w, __shfl_xor(w, off, 64));
        if (threadIdx.x == 0) atomicMax(&scal[0], fkey(w));
    } else {
        int m = (blockIdx.x - 256) * 64 + threadIdx.x;
        const float4* p = (const float4*)(cb + (size_t)m * DIM);
        const size_t fragbase = (size_t)((m >> 4) * 8) * 64 + (m & 15);
        float acc = 0.f;
        for (int k8 = 0; k8 < 32; ++k8) {
            float4 v0 = p[2 * k8], v1 = p[2 * k8 + 1];
            acc += v0.x * v0.x + v0.y * v0.y + v0.z * v0.z + v0.w * v0.w;
            acc += v1.x * v1.x + v1.y * v1.y + v1.z * v1.z + v1.w * v1.w;
            v8h val;
            val[0] = (_Float16)(v0.x * 16384.0f); val[1] = (_Float16)(v0.y * 16384.0f);
            val[2] = (_Float16)(v0.z * 16384.0f); val[3] = (_Float16)(v0.w * 16384.0f);
            val[4] = (_Float16)(v1.x * 16384.0f); val[5] = (_Float16)(v1.y * 16384.0f);
            val[6] = (_Float16)(v1.z * 16384.0f); val[7] = (_Float16)(v1.w * 16384.0f);
            int ks = k8 >> 2, qq = k8 & 3;
            *(v8h*)(chf + (fragbase + (size_t)ks * 64 + qq * 16) * 8) = val;
        }
        float w = acc;
        #pragma unroll
        for (int off = 1; off < 64; off <<= 1) w = fmaxf(w, __shfl_xor(w, off, 64));
        if (threadIdx.x == 0) atomicMax(&scal[1], fkey(w));
    }
}

// Margin kernel: scal[2] = M' (keeps collect at 60 VGPR — r12/r13 lesson).
__global__ void vq_margin(unsigned* scal) {
    ((float*)scal)[2] = margin_from(scal);
}

// ===========================================================================
// Seed (rf=2, r14-proven): per-row max of approx dot over the 1/4 column
// subsample (chunks chunk0 + 4*it); every wave scans all 16 sampled chunks.
__global__ __attribute__((amdgpu_flat_work_group_size(256, 256), amdgpu_waves_per_eu(1, 4)))
void vq_seed(const v8h* __restrict__ zhf, const char* __restrict__ cbytes,
             unsigned* __restrict__ dotmax) {
    __shared__ __align__(16) char Bt[3][8192];
    const int tid  = threadIdx.x;
    const int wave = tid >> 6, lane = tid & 63;
    const int rowbase = blockIdx.y * 128 + wave * 32;
    const int hi = (lane >> 4) & 3;

    v8h a[2][8];
    const int g16b = rowbase >> 4;
    #pragma unroll
    for (int rf = 0; rf < 2; ++rf)
        #pragma unroll
        for (int ks = 0; ks < 8; ++ks)
            a[rf][ks] = zhf[(size_t)((g16b + rf) * 8 + ks) * 64 + lane];

    float runm[2][4];
    #pragma unroll
    for (int rf = 0; rf < 2; ++rf)
        #pragma unroll
        for (int r = 0; r < 4; ++r) runm[rf][r] = -1e30f;

    const int chunk0 = blockIdx.x * 64;
    const int sb = wave * 2048 + lane * 16;

    #pragma unroll
    for (int p = 0; p < 2; ++p) {
        const char* src = cbytes + (size_t)(chunk0 + p * 4) * 8192 + sb;
        char*       dst = &Bt[p][sb];
        gll16(src, dst);
        gll16(src + 1024, dst + 1024);
    }

    for (int it = 0; it < 16; ++it) {
        asm volatile("s_waitcnt vmcnt(2)" ::: "memory");
        __builtin_amdgcn_sched_barrier(0);
        __builtin_amdgcn_s_barrier();
        __builtin_amdgcn_sched_barrier(0);
        {
            int st = (it + 2 <= 15) ? (it + 2) : 15;    // clamp: dead restage at tail
            const char* src = cbytes + (size_t)(chunk0 + st * 4) * 8192 + sb;
            char*       dst = &Bt[(it + 2) % 3][sb];
            gll16(src, dst);
            gll16(src + 1024, dst + 1024);
        }
        const char* bt = Bt[it % 3];
        f32x4 acc[2];
        acc[0] = (f32x4){0.f, 0.f, 0.f, 0.f};
        acc[1] = (f32x4){0.f, 0.f, 0.f, 0.f};
        __builtin_amdgcn_s_setprio(1);
        #pragma unroll
        for (int ks = 0; ks < 8; ++ks) {
            v8h b0 = *(const v8h*)(bt + (size_t)ks * 1024 + lane * 16);
            acc[0] = __builtin_amdgcn_mfma_f32_16x16x32_f16(a[0][ks], b0, acc[0], 0, 0, 0);
            acc[1] = __builtin_amdgcn_mfma_f32_16x16x32_f16(a[1][ks], b0, acc[1], 0, 0, 0);
        }
        __builtin_amdgcn_s_setprio(0);
        #pragma unroll
        for (int rf = 0; rf < 2; ++rf)
            #pragma unroll
            for (int r = 0; r < 4; ++r)
                runm[rf][r] = fmaxf(runm[rf][r], acc[rf][r]);
    }

    #pragma unroll
    for (int rf = 0; rf < 2; ++rf)
        #pragma unroll
        for (int r = 0; r < 4; ++r) {
            float v = runm[rf][r];
            v = fmaxf(v, __shfl_xor(v, 1, 64));
            v = fmaxf(v, __shfl_xor(v, 2, 64));
            v = fmaxf(v, __shfl_xor(v, 4, 64));
            v = fmaxf(v, __shfl_xor(v, 8, 64));
            if ((lane & 15) == 0)
                atomicMax(&dotmax[rowbase + rf * 16 + hi * 4 + r], fkey(v));
        }
}

// Collect (rf=2, r13/r14-proven: 60 VGPR, ~155 us): full sweep, thr =
// seed_max - scal[2] (precomputed M). Every wave scans all 64 chunks.
__global__ __attribute__((amdgpu_flat_work_group_size(256, 256), amdgpu_waves_per_eu(1, 4)))
void vq_collect(const v8h* __restrict__ zhf, const char* __restrict__ cbytes,
                const unsigned* __restrict__ dotmax, const unsigned* __restrict__ scal,
                unsigned* __restrict__ cnt, unsigned* __restrict__ cand) {
    __shared__ __align__(16) char Bt[3][8192];
    const int tid  = threadIdx.x;
    const int wave = tid >> 6, lane = tid & 63;
    const int rowbase = blockIdx.y * 128 + wave * 32;
    const int hi = (lane >> 4) & 3;

    v8h a[2][8];
    const int g16b = rowbase >> 4;
    #pragma unroll
    for (int rf = 0; rf < 2; ++rf)
        #pragma unroll
        for (int ks = 0; ks < 8; ++ks)
            a[rf][ks] = zhf[(size_t)((g16b + rf) * 8 + ks) * 64 + lane];

    const float M = ((const float*)scal)[2];
    float thrv[2][4];
    #pragma unroll
    for (int rf = 0; rf < 2; ++rf)
        #pragma unroll
        for (int r = 0; r < 4; ++r)
            thrv[rf][r] = fdec(dotmax[rowbase + rf * 16 + hi * 4 + r]) - M;

    const int chunk0 = blockIdx.x * 64;
    const int sb = wave * 2048 + lane * 16;

    #pragma unroll
    for (int p = 0; p < 2; ++p) {
        const char* src = cbytes + (size_t)(chunk0 + p) * 8192 + sb;
        char*       dst = &Bt[p][sb];
        gll16(src, dst);
        gll16(src + 1024, dst + 1024);
    }

    for (int t = 0; t < 64; ++t) {
        asm volatile("s_waitcnt vmcnt(2)" ::: "memory");
        __builtin_amdgcn_sched_barrier(0);
        __builtin_amdgcn_s_barrier();
        __builtin_amdgcn_sched_barrier(0);
        {
            int st_t = (t + 2 <= 63) ? (t + 2) : 63;
            const char* src = cbytes + (size_t)(chunk0 + st_t) * 8192 + sb;
            char*       dst = &Bt[(t + 2) % 3][sb];
            gll16(src, dst);
            gll16(src + 1024, dst + 1024);
        }
        const char* bt = Bt[t % 3];
        f32x4 acc[2];
        acc[0] = (f32x4){0.f, 0.f, 0.f, 0.f};
        acc[1] = (f32x4){0.f, 0.f, 0.f, 0.f};
        __builtin_amdgcn_s_setprio(1);
        #pragma unroll
        for (int ks = 0; ks < 8; ++ks) {
            v8h b0 = *(const v8h*)(bt + (size_t)ks * 1024 + lane * 16);
            acc[0] = __builtin_amdgcn_mfma_f32_16x16x32_f16(a[0][ks], b0, acc[0], 0, 0, 0);
            acc[1] = __builtin_amdgcn_mfma_f32_16x16x32_f16(a[1][ks], b0, acc[1], 0, 0, 0);
        }
        __builtin_amdgcn_s_setprio(0);
        bool hit = false;
        #pragma unroll
        for (int rf = 0; rf < 2; ++rf)
            #pragma unroll
            for (int r = 0; r < 4; ++r)
                hit = hit || (acc[rf][r] >= thrv[rf][r]);
        if (__any(hit)) {
            #pragma unroll
            for (int rf = 0; rf < 2; ++rf)
                #pragma unroll
                for (int r = 0; r < 4; ++r)
                    if (acc[rf][r] >= thrv[rf][r]) {
                        int row = rowbase + rf * 16 + hi * 4 + r;
                        int col = (chunk0 + t) * 16 + (lane & 15);
                        unsigned pos = atomicAdd(&cnt[row], 1u);
                        if (pos < (unsigned)CAP2)
                            cand[(size_t)row * CAP2 + pos] = (unsigned)col;
                    }
        }
    }
}

// ===========================================================================
// Two-pass fallback GEMM (r8-proven barrier shape, rf=2) — untouched.
template <int COLLECT, int CAPN>
__global__ __attribute__((amdgpu_flat_work_group_size(256, 256), amdgpu_waves_per_eu(1, 4)))
void vq_gemm(const v8h* __restrict__ zhf, const char* __restrict__ cbytes,
             unsigned* __restrict__ dotmax, const unsigned* __restrict__ scal,
             unsigned* __restrict__ cnt, unsigned* __restrict__ cand) {
    __shared__ __align__(16) char Bt[3][8192];
    const int tid  = threadIdx.x;
    const int wave = tid >> 6, lane = tid & 63;
    const int rowbase = blockIdx.y * 128 + wave * 32;
    const int hi = (lane >> 4) & 3;

    v8h a[2][8];
    const int g16b = rowbase >> 4;
    #pragma unroll
    for (int rf = 0; rf < 2; ++rf)
        #pragma unroll
        for (int ks = 0; ks < 8; ++ks)
            a[rf][ks] = zhf[(size_t)((g16b + rf) * 8 + ks) * 64 + lane];

    float thrv[2][4];
    if (COLLECT) {
        float M = ((const float*)scal)[2];
        #pragma unroll
        for (int rf = 0; rf < 2; ++rf)
            #pragma unroll
            for (int r = 0; r < 4; ++r)
                thrv[rf][r] = fdec(dotmax[rowbase + rf * 16 + hi * 4 + r]) - M;
    }
    float runm[2][4];
    if (!COLLECT) {
        #pragma unroll
        for (int rf = 0; rf < 2; ++rf)
            #pragma unroll
            for (int r = 0; r < 4; ++r) runm[rf][r] = -1e30f;
    }

    const int chunk0 = blockIdx.x * 64;
    const int sb = wave * 2048 + lane * 16;

    #pragma unroll
    for (int p = 0; p < 2; ++p) {
        const char* src = cbytes + (size_t)(chunk0 + p) * 8192 + sb;
        char*       dst = &Bt[p][sb];
        gll16(src, dst);
        gll16(src + 1024, dst + 1024);
    }

    for (int t = 0; t < 64; ++t) {
        asm volatile("s_waitcnt vmcnt(2)" ::: "memory");
        __builtin_amdgcn_sched_barrier(0);
        __builtin_amdgcn_s_barrier();
        __builtin_amdgcn_sched_barrier(0);
        {
            int st_t = (t + 2 <= 63) ? (t + 2) : 63;
            const char* src = cbytes + (size_t)(chunk0 + st_t) * 8192 + sb;
            char*       dst = &Bt[(t + 2) % 3][sb];
            gll16(src, dst);
            gll16(src + 1024, dst + 1024);
        }
        const char* bt = Bt[t % 3];
        f32x4 acc[2];
        acc[0] = (f32x4){0.f, 0.f, 0.f, 0.f};
        acc[1] = (f32x4){0.f, 0.f, 0.f, 0.f};
        #pragma unroll
        for (int ks = 0; ks < 8; ++ks) {
            v8h b0 = *(const v8h*)(bt + (size_t)ks * 1024 + lane * 16);
            acc[0] = __builtin_amdgcn_mfma_f32_16x16x32_f16(a[0][ks], b0, acc[0], 0, 0, 0);
            acc[1] = __builtin_amdgcn_mfma_f32_16x16x32_f16(a[1][ks], b0, acc[1], 0, 0, 0);
        }
        if (!COLLECT) {
            #pragma unroll
            for (int rf = 0; rf < 2; ++rf)
                #pragma unroll
                for (int r = 0; r < 4; ++r)
                    runm[rf][r] = fmaxf(runm[rf][r], acc[rf][r]);
        } else {
            bool hit = false;
            #pragma unroll
            for (int rf = 0; rf < 2; ++rf)
                #pragma unroll
                for (int r = 0; r < 4; ++r)
                    hit = hit || (acc[rf][r] >= thrv[rf][r]);
            if (__any(hit)) {
                #pragma unroll
                for (int rf = 0; rf < 2; ++rf)
                    #pragma unroll
                    for (int r = 0; r < 4; ++r)
                        if (acc[rf][r] >= thrv[rf][r]) {
                            int row = rowbase + rf * 16 + hi * 4 + r;
                            int col = (chunk0 + t) * 16 + (lane & 15);
                            unsigned pos = atomicAdd(&cnt[row], 1u);
                            if (pos < (unsigned)CAPN)
                                cand[(size_t)row * CAPN + pos] = (unsigned)col;
                        }
            }
        }
    }

    if (!COLLECT) {
        #pragma unroll
        for (int rf = 0; rf < 2; ++rf)
            #pragma unroll
            for (int r = 0; r < 4; ++r) {
                float v = runm[rf][r];
                v = fmaxf(v, __shfl_xor(v, 1, 64));
                v = fmaxf(v, __shfl_xor(v, 2, 64));
                v = fmaxf(v, __shfl_xor(v, 4, 64));
                v = fmaxf(v, __shfl_xor(v, 8, 64));
                if ((lane & 15) == 0)
                    atomicMax(&dotmax[rowbase + rf * 16 + hi * 4 + r], fkey(v));
            }
    }
}

// ===========================================================================
// Exact finish (4 rows per 256-thread block; wave r owns row 4*bid+r — waves
// fully independent, all shuffles width-64 intra-wave). fp64 re-eval of
// candidates, lexmin (fl32 d, m); overflow/empty -> exact full scan.
template <int C>
__global__ void vq_finish(const float* __restrict__ zt, const float* __restrict__ cb,
                          const float* __restrict__ zs32,
                          const unsigned* __restrict__ cnt, const unsigned* __restrict__ cand,
                          float* __restrict__ outq, float* __restrict__ outi) {
    const int row  = blockIdx.x * 4 + (threadIdx.x >> 6);
    const int lane = threadIdx.x & 63;
    const unsigned nc = cnt[row];
    const double zs = (double)zs32[row];
    float bd = __builtin_huge_valf();
    int   bi = 0x7fffffff;

    if (nc >= 1u && nc <= (unsigned)C) {
        const float4 zv = *(const float4*)(zt + (size_t)row * DIM + lane * 4);
        for (unsigned i = 0; i < nc; ++i) {
            int m = (int)cand[(size_t)row * C + i];
            const float4 ev = *(const float4*)(cb + (size_t)m * DIM + lane * 4);
            double s = (double)zv.x * (double)ev.x + (double)zv.y * (double)ev.y
                     + (double)zv.z * (double)ev.z + (double)zv.w * (double)ev.w;
            #pragma unroll
            for (int off = 1; off < 64; off <<= 1) s += __shfl_xor(s, off, 64);
            float d = (float)(zs - 2.0 * s);
            if (d < bd || (d == bd && m < bi)) { bd = d; bi = m; }
        }
    } else {
        const float4* zr4 = (const float4*)(zt + (size_t)row * DIM);
        float lbd = __builtin_huge_valf();
        int   lbi = 0x7fffffff;
        for (int rep = 0; rep < NCODES / 64; ++rep) {
            int m = rep * 64 + lane;
            const float4* er4 = (const float4*)(cb + (size_t)m * DIM);
            double s0 = 0.0, s1 = 0.0;
            #pragma unroll 4
            for (int c4 = 0; c4 < DIM / 8; ++c4) {
                float4 z4 = zr4[c4], e4 = er4[c4];
                float4 z5 = zr4[c4 + 32], e5 = er4[c4 + 32];
                s0 += (double)z4.x * (double)e4.x + (double)z4.y * (double)e4.y
                    + (double)z4.z * (double)e4.z + (double)z4.w * (double)e4.w;
                s1 += (double)z5.x * (double)e5.x + (double)z5.y * (double)e5.y
                    + (double)z5.z * (double)e5.z + (double)z5.w * (double)e5.w;
            }
            double s = s0 + s1;
            float d = (float)(zs - 2.0 * s);
            if (d < lbd || (d == lbd && m < lbi)) { lbd = d; lbi = m; }
        }
        #pragma unroll
        for (int off = 1; off < 64; off <<= 1) {
            float od = __shfl_xor(lbd, off, 64);
            int   oi = __shfl_xor(lbi, off, 64);
            if (od < lbd || (od == lbd && oi < lbi)) { lbd = od; lbi = oi; }
        }
        bd = lbd; bi = lbi;
    }

    if (lane == 0) outi[row] = (float)bi;
    float4 v = *(const float4*)(cb + (size_t)bi * DIM + lane * 4);
    *(float4*)(outq + (size_t)row * DIM + lane * 4) = v;
}

// ===========================================================================
// Round-2 proven fallback path (only if ws is too small for both fast paths).
__global__ void vq_zsum32(const float* __restrict__ z, float* __restrict__ zs) {
    int n = blockIdx.x * 64 + threadIdx.x;
    int b = n >> 10, hw = n & 1023;
    const float* p = z + (size_t)b * (DIM * 1024) + hw;
    float h[2];
    #pragma unroll
    for (int half = 0; half < 2; ++half) {
        const float* q = p + (size_t)(half * 128) * 1024;
        float r[8];
        #pragma unroll
        for (int j = 0; j < 8; ++j) { float v = q[(size_t)j * 1024]; r[j] = __fmul_rn(v, v); }
        for (int i = 8; i < 128; i += 8)
            #pragma unroll
            for (int j = 0; j < 8; ++j) {
                float v = q[(size_t)(i + j) * 1024];
                r[j] = __fadd_rn(r[j], __fmul_rn(v, v));
            }
        float s01 = __fadd_rn(r[0], r[1]), s23 = __fadd_rn(r[2], r[3]);
        float s45 = __fadd_rn(r[4], r[5]), s67 = __fadd_rn(r[6], r[7]);
        h[half] = __fadd_rn(__fadd_rn(s01, s23), __fadd_rn(s45, s67));
    }
    zs[n] = __fadd_rn(h[0], h[1]);
}

__global__ __launch_bounds__(256, 2)
void vq_main(const float* __restrict__ z, const float* __restrict__ cb,
             const float* __restrict__ zs32, int* __restrict__ outidx) {
    __shared__ __align__(16) float ztl[32][260];
    __shared__ __align__(16) float et[16][260];
    const int tid = threadIdx.x;
    const int n0 = blockIdx.x * 32;
    const int b = n0 >> 10, hw0 = n0 & 1023;
    const float* zb = z + (size_t)b * (DIM * 1024) + hw0;
    for (int i = tid; i < 32 * DIM; i += 256) {
        int r = i & 31, c = i >> 5;
        ztl[r][c] = zb[(size_t)c * 1024 + r];
    }
    const int cg = tid & 15, rg = tid >> 4;
    const int r0 = rg * 2, r1 = r0 + 1;
    const float zsa = zs32[n0 + r0], zsb = zs32[n0 + r1];
    float b0d = __builtin_huge_valf(), b1d = __builtin_huge_valf();
    int b0i = 0, b1i = 0;
    for (int m0 = 0; m0 < NCODES; m0 += 16) {
        __syncthreads();
        for (int i = tid; i < 16 * 64; i += 256) {
            int m = i >> 6, q = i & 63;
            float4 v = *(const float4*)(cb + (size_t)(m0 + m) * DIM + q * 4);
            *(float4*)&et[m][q * 4] = v;
        }
        __syncthreads();
        double a0 = 0.0, a1 = 0.0;
        #pragma unroll 8
        for (int k4 = 0; k4 < DIM / 4; ++k4) {
            float4 ev = *(const float4*)&et[cg][k4 * 4];
            float4 z0 = *(const float4*)&ztl[r0][k4 * 4];
            float4 z1 = *(const float4*)&ztl[r1][k4 * 4];
            double e0 = ev.x, e1 = ev.y, e2 = ev.z, e3 = ev.w;
            a0 += (double)z0.x * e0; a1 += (double)z1.x * e0;
            a0 += (double)z0.y * e1; a1 += (double)z1.y * e1;
            a0 += (double)z0.z * e2; a1 += (double)z1.z * e2;
            a0 += (double)z0.w * e3; a1 += (double)z1.w * e3;
        }
        const int m = m0 + cg;
        float d0 = (float)((double)zsa - 2.0 * a0);
        float d1 = (float)((double)zsb - 2.0 * a1);
        if (d0 < b0d) { b0d = d0; b0i = m; }
        if (d1 < b1d) { b1d = d1; b1i = m; }
    }
    #pragma unroll
    for (int off = 1; off < 16; off <<= 1) {
        float od0 = __shfl_xor(b0d, off, 64); int oi0 = __shfl_xor(b0i, off, 64);
        if (od0 < b0d || (od0 == b0d && oi0 < b0i)) { b0d = od0; b0i = oi0; }
        float od1 = __shfl_xor(b1d, off, 64); int oi1 = __shfl_xor(b1i, off, 64);
        if (od1 < b1d || (od1 == b1d && oi1 < b1i)) { b1d = od1; b1i = oi1; }
    }
    if (cg == 0) { outidx[n0 + r0] = b0i; outidx[n0 + r1] = b1i; }
}

__global__ void vq_gather(const float* __restrict__ cb, const int* __restrict__ idx,
                          float* __restrict__ outq, float* __restrict__ outi) {
    int n = blockIdx.x, t = threadIdx.x;
    int m = idx[n];
    float4 v = *(const float4*)(cb + (size_t)m * DIM + t * 4);
    *(float4*)(outq + (size_t)n * DIM + t * 4) = v;
    if (t == 0) outi[n] = (float)m;
}

// ===========================================================================
extern "C" void kernel_launch(void* const* d_in, const int* in_sizes, int n_in,
                              void* d_out, int out_size, void* d_ws, size_t ws_size,
                              hipStream_t stream) {
    const float* z  = (const float*)d_in[0];
    const float* cb = (const float*)d_in[1];
    float* outq = (float*)d_out;
    float* outi = outq + (size_t)NROWS * DIM;
    char* ws = (char*)d_ws;

    if (ws_size >= NWS_NEEDED) {
        // ---- seeded path: merged prep, margin kernel, rf=2 seed+collect ----
        float*     zt     = (float*)(ws + NWS_ZT);
        _Float16*  zhf    = (_Float16*)(ws + NWS_ZHF);
        _Float16*  chf    = (_Float16*)(ws + NWS_CHF);
        float*     zs32   = (float*)(ws + NWS_ZS);
        unsigned*  dotmax = (unsigned*)(ws + NWS_DOTMAX);
        unsigned*  cnt    = (unsigned*)(ws + NWS_CNT);
        unsigned*  scal   = (unsigned*)(ws + NWS_SCAL);
        unsigned*  cand   = (unsigned*)(ws + NWS_CAND);

        // dotmax(64K) + cnt(64K) + scal(256B) contiguous: one memset
        hipMemsetAsync(dotmax, 0, 65536 + 65536 + 256, stream);

        vq_prep    <<<512, 64, 0, stream>>>(z, zt, zs32, zhf, cb, chf, scal);
        vq_margin  <<<1, 1, 0, stream>>>(scal);
        vq_seed    <<<dim3(16, 128), 256, 0, stream>>>((const v8h*)zhf, (const char*)chf,
                                                       dotmax);
        vq_collect <<<dim3(16, 128), 256, 0, stream>>>((const v8h*)zhf, (const char*)chf,
                                                       dotmax, scal, cnt, cand);
        vq_finish<CAP2><<<NROWS / 4, 256, 0, stream>>>(zt, cb, zs32, cnt, cand, outq, outi);
    } else if (ws_size >= WS_NEEDED) {
        // -------- r8-proven two-pass path --------
        float*     zt     = (float*)(ws + WS_ZT);
        _Float16*  zhf    = (_Float16*)(ws + WS_ZHF);
        _Float16*  chf    = (_Float16*)(ws + WS_CHF);
        float*     zs32   = (float*)(ws + WS_ZS);
        unsigned*  dotmax = (unsigned*)(ws + WS_DOTMAX);
        unsigned*  cnt    = (unsigned*)(ws + WS_CNT);
        unsigned*  cand   = (unsigned*)(ws + WS_CAND);
        unsigned*  scal   = (unsigned*)(ws + WS_SCAL);

        hipMemsetAsync(dotmax, 0, 65536, stream);
        hipMemsetAsync(cnt,    0, 65536, stream);
        hipMemsetAsync(scal,   0, 256,   stream);

        vq_prep    <<<512, 64, 0, stream>>>(z, zt, zs32, zhf, cb, chf, scal);
        vq_margin  <<<1, 1, 0, stream>>>(scal);
        vq_gemm<0, CAP><<<dim3(16, 128), 256, 0, stream>>>((const v8h*)zhf, (const char*)chf,
                                                           dotmax, scal, cnt, cand);
        vq_gemm<1, CAP><<<dim3(16, 128), 256, 0, stream>>>((const v8h*)zhf, (const char*)chf,
                                                           dotmax, scal, cnt, cand);
        vq_finish<CAP><<<NROWS / 4, 256, 0, stream>>>(zt, cb, zs32, cnt, cand, outq, outi);
    } else {
        float* zs32 = (float*)d_ws;
        int*   idx  = (int*)(zs32 + NROWS);
        vq_zsum32<<<NROWS / 64, 64, 0, stream>>>(z, zs32);
        vq_main  <<<NROWS / 32, 256, 0, stream>>>(z, cb, zs32, idx);
        vq_gather<<<NROWS, 64, 0, stream>>>(cb, idx, outq, outi);
    }
}

// Round 17
// 255.209 us; speedup vs baseline: 1.0655x; 1.0655x over previous
//
#include <hip/hip_runtime.h>

#define NROWS  16384
#define NCODES 16384
#define DIM    256
#define CAP    15          // two-pass fallback candidates/row (r8-proven)
#define CAP2   96          // seeded path candidates/row (r10-proven)

typedef __attribute__((ext_vector_type(8))) _Float16 v8h;   // fp16x8 MFMA operand
typedef __attribute__((ext_vector_type(4))) float    f32x4; // MFMA 16x16 accum

// ---------------- two-pass fallback ws layout (r3-r8 proven: 34,734,336) -------
#define WS_ZT      0ULL
#define WS_ZHF     16777216ULL
#define WS_CHF     25165824ULL
#define WS_ZS      33554432ULL
#define WS_DOTMAX  33619968ULL
#define WS_CNT     33685504ULL
#define WS_CAND    33751040ULL
#define WS_SCAL    34734080ULL
#define WS_NEEDED  34734336ULL

// ---------------- seeded-path ws layout (40,042,752; granted r9-r16) -----------
#define NWS_ZT      0ULL          // float    z_t[16384][256]        16 MB
#define NWS_ZHF     16777216ULL   // _Float16 z frags                 8 MB
#define NWS_CHF     25165824ULL   // _Float16 cb frags (x 2^14)       8 MB
#define NWS_ZS      33554432ULL   // float    zs32[16384]            64 KB
#define NWS_DOTMAX  33619968ULL   // uint     dotmax key[16384]      64 KB
#define NWS_CNT     33685504ULL   // uint     cnt[16384]             64 KB
#define NWS_SCAL    33751040ULL   // uint     [0]=zsmax [1]=esmax [2]=M'  256 B
#define NWS_CAND    33751296ULL   // uint     cand[16384][CAP2]       6 MB
#define NWS_NEEDED  40042752ULL

__device__ inline unsigned fkey(float f) {
    unsigned u = __float_as_uint(f);
    return (u & 0x80000000u) ? ~u : (u | 0x80000000u);
}
__device__ inline float fdec(unsigned k) {
    unsigned u = (k & 0x80000000u) ? (k ^ 0x80000000u) : ~k;
    return __uint_as_float(u);
}
// Screening margin in SCALED dot units (dot' = dot * 2^14); r4-r16-proven
// formula. Computed ONLY in the tiny vq_margin kernel (r12/r13 lesson:
// inlining costs 8 VGPR -> crosses 64-granule -> -33% collect).
__device__ inline float margin_from(const unsigned* scal) {
    float zsM = fdec(scal[0]) * 1.0001f;
    float esM = fdec(scal[1]) * 1.0001f;
    float delta = 1.1e-3f * sqrtf(zsM * esM) + 2e-6f;
    return 16384.0f * (1.25f * (2.0f * delta + 3.2e-5f));
}
// async 16B global->LDS (gfx950); vmcnt-tracked, LDS dest = wave base + lane*16
__device__ inline void gll16(const void* g, void* s) {
    __builtin_amdgcn_global_load_lds(
        (const __attribute__((address_space(1))) unsigned int*)g,
        (__attribute__((address_space(3))) unsigned int*)s, 16, 0, 0);
}

// ===========================================================================
// MERGED prep (r14-proven): blocks 0-255 = prep_z body (zs32 numpy-pairwise +
// zt transpose + fused f16 pack + scal[0]); blocks 256-511 = prep_cb body.
__global__ void vq_prep(const float* __restrict__ z, float* __restrict__ zt,
                        float* __restrict__ zs, _Float16* __restrict__ zhf,
                        const float* __restrict__ cb, _Float16* __restrict__ chf,
                        unsigned* __restrict__ scal) {
    if (blockIdx.x < 256) {
        int n = blockIdx.x * 64 + threadIdx.x;
        int b = n >> 10, hw = n & 1023;
        const float* p = z + (size_t)b * (DIM * 1024) + hw;
        float* zrow = zt + (size_t)n * DIM;
        const size_t fragbase = (size_t)((n >> 4) * 8) * 64 + (n & 15);
        float h[2];
        #pragma unroll
        for (int half = 0; half < 2; ++half) {
            const float* q = p + (size_t)(half * 128) * 1024;
            float* qr = zrow + half * 128;
            float r[8];
            v8h val;
            #pragma unroll
            for (int j = 0; j < 8; ++j) {
                float v = q[(size_t)j * 1024];
                qr[j] = v;
                r[j] = __fmul_rn(v, v);
                val[j] = (_Float16)v;
            }
            *(v8h*)(zhf + (fragbase + (size_t)(half * 4) * 64) * 8) = val;
            for (int i = 8; i < 128; i += 8) {
                #pragma unroll
                for (int j = 0; j < 8; ++j) {
                    float v = q[(size_t)(i + j) * 1024];
                    qr[i + j] = v;
                    r[j] = __fadd_rn(r[j], __fmul_rn(v, v));
                    val[j] = (_Float16)v;
                }
                int ks = half * 4 + (i >> 5), qq = (i >> 3) & 3;
                *(v8h*)(zhf + (fragbase + (size_t)ks * 64 + qq * 16) * 8) = val;
            }
            float s01 = __fadd_rn(r[0], r[1]), s23 = __fadd_rn(r[2], r[3]);
            float s45 = __fadd_rn(r[4], r[5]), s67 = __fadd_rn(r[6], r[7]);
            h[half] = __fadd_rn(__fadd_rn(s01, s23), __fadd_rn(s45, s67));
        }
        float total = __fadd_rn(h[0], h[1]);
        zs[n] = total;
        float w = total;
        #pragma unroll
        for (int off = 1; off < 64; off <<= 1) w = fmaxf(w, __shfl_xor(w, off, 64));
        if (threadIdx.x == 0) atomicMax(&scal[0], fkey(w));
    } else {
        int m = (blockIdx.x - 256) * 64 + threadIdx.x;
        const float4* p = (const float4*)(cb + (size_t)m * DIM);
        const size_t fragbase = (size_t)((m >> 4) * 8) * 64 + (m & 15);
        float acc = 0.f;
        for (int k8 = 0; k8 < 32; ++k8) {
            float4 v0 = p[2 * k8], v1 = p[2 * k8 + 1];
            acc += v0.x * v0.x + v0.y * v0.y + v0.z * v0.z + v0.w * v0.w;
            acc += v1.x * v1.x + v1.y * v1.y + v1.z * v1.z + v1.w * v1.w;
            v8h val;
            val[0] = (_Float16)(v0.x * 16384.0f); val[1] = (_Float16)(v0.y * 16384.0f);
            val[2] = (_Float16)(v0.z * 16384.0f); val[3] = (_Float16)(v0.w * 16384.0f);
            val[4] = (_Float16)(v1.x * 16384.0f); val[5] = (_Float16)(v1.y * 16384.0f);
            val[6] = (_Float16)(v1.z * 16384.0f); val[7] = (_Float16)(v1.w * 16384.0f);
            int ks = k8 >> 2, qq = k8 & 3;
            *(v8h*)(chf + (fragbase + (size_t)ks * 64 + qq * 16) * 8) = val;
        }
        float w = acc;
        #pragma unroll
        for (int off = 1; off < 64; off <<= 1) w = fmaxf(w, __shfl_xor(w, off, 64));
        if (threadIdx.x == 0) atomicMax(&scal[1], fkey(w));
    }
}

// Margin kernel: scal[2] = M' (keeps collect at 60 VGPR — r12/r13 lesson).
__global__ void vq_margin(unsigned* scal) {
    ((float*)scal)[2] = margin_from(scal);
}

// ===========================================================================
// Seed (rf=2, r14-proven): per-row max of approx dot over the 1/4 column
// subsample (chunks chunk0 + 4*it); every wave scans all 16 sampled chunks.
__global__ __attribute__((amdgpu_flat_work_group_size(256, 256), amdgpu_waves_per_eu(1, 4)))
void vq_seed(const v8h* __restrict__ zhf, const char* __restrict__ cbytes,
             unsigned* __restrict__ dotmax) {
    __shared__ __align__(16) char Bt[3][8192];
    const int tid  = threadIdx.x;
    const int wave = tid >> 6, lane = tid & 63;
    const int rowbase = blockIdx.y * 128 + wave * 32;
    const int hi = (lane >> 4) & 3;

    v8h a[2][8];
    const int g16b = rowbase >> 4;
    #pragma unroll
    for (int rf = 0; rf < 2; ++rf)
        #pragma unroll
        for (int ks = 0; ks < 8; ++ks)
            a[rf][ks] = zhf[(size_t)((g16b + rf) * 8 + ks) * 64 + lane];

    float runm[2][4];
    #pragma unroll
    for (int rf = 0; rf < 2; ++rf)
        #pragma unroll
        for (int r = 0; r < 4; ++r) runm[rf][r] = -1e30f;

    const int chunk0 = blockIdx.x * 64;
    const int sb = wave * 2048 + lane * 16;

    #pragma unroll
    for (int p = 0; p < 2; ++p) {
        const char* src = cbytes + (size_t)(chunk0 + p * 4) * 8192 + sb;
        char*       dst = &Bt[p][sb];
        gll16(src, dst);
        gll16(src + 1024, dst + 1024);
    }

    for (int it = 0; it < 16; ++it) {
        asm volatile("s_waitcnt vmcnt(2)" ::: "memory");
        __builtin_amdgcn_sched_barrier(0);
        __builtin_amdgcn_s_barrier();
        __builtin_amdgcn_sched_barrier(0);
        {
            int st = (it + 2 <= 15) ? (it + 2) : 15;    // clamp: dead restage at tail
            const char* src = cbytes + (size_t)(chunk0 + st * 4) * 8192 + sb;
            char*       dst = &Bt[(it + 2) % 3][sb];
            gll16(src, dst);
            gll16(src + 1024, dst + 1024);
        }
        const char* bt = Bt[it % 3];
        f32x4 acc[2];
        acc[0] = (f32x4){0.f, 0.f, 0.f, 0.f};
        acc[1] = (f32x4){0.f, 0.f, 0.f, 0.f};
        __builtin_amdgcn_s_setprio(1);
        #pragma unroll
        for (int ks = 0; ks < 8; ++ks) {
            v8h b0 = *(const v8h*)(bt + (size_t)ks * 1024 + lane * 16);
            acc[0] = __builtin_amdgcn_mfma_f32_16x16x32_f16(a[0][ks], b0, acc[0], 0, 0, 0);
            acc[1] = __builtin_amdgcn_mfma_f32_16x16x32_f16(a[1][ks], b0, acc[1], 0, 0, 0);
        }
        __builtin_amdgcn_s_setprio(0);
        #pragma unroll
        for (int rf = 0; rf < 2; ++rf)
            #pragma unroll
            for (int r = 0; r < 4; ++r)
                runm[rf][r] = fmaxf(runm[rf][r], acc[rf][r]);
    }

    #pragma unroll
    for (int rf = 0; rf < 2; ++rf)
        #pragma unroll
        for (int r = 0; r < 4; ++r) {
            float v = runm[rf][r];
            v = fmaxf(v, __shfl_xor(v, 1, 64));
            v = fmaxf(v, __shfl_xor(v, 2, 64));
            v = fmaxf(v, __shfl_xor(v, 4, 64));
            v = fmaxf(v, __shfl_xor(v, 8, 64));
            if ((lane & 15) == 0)
                atomicMax(&dotmax[rowbase + rf * 16 + hi * 4 + r], fkey(v));
        }
}

// Collect (rf=2, r13/r14/r16-proven: 60 VGPR, ~156 us): full sweep, thr =
// seed_max - scal[2] (precomputed M). Every wave scans all 64 chunks.
__global__ __attribute__((amdgpu_flat_work_group_size(256, 256), amdgpu_waves_per_eu(1, 4)))
void vq_collect(const v8h* __restrict__ zhf, const char* __restrict__ cbytes,
                const unsigned* __restrict__ dotmax, const unsigned* __restrict__ scal,
                unsigned* __restrict__ cnt, unsigned* __restrict__ cand) {
    __shared__ __align__(16) char Bt[3][8192];
    const int tid  = threadIdx.x;
    const int wave = tid >> 6, lane = tid & 63;
    const int rowbase = blockIdx.y * 128 + wave * 32;
    const int hi = (lane >> 4) & 3;

    v8h a[2][8];
    const int g16b = rowbase >> 4;
    #pragma unroll
    for (int rf = 0; rf < 2; ++rf)
        #pragma unroll
        for (int ks = 0; ks < 8; ++ks)
            a[rf][ks] = zhf[(size_t)((g16b + rf) * 8 + ks) * 64 + lane];

    const float M = ((const float*)scal)[2];
    float thrv[2][4];
    #pragma unroll
    for (int rf = 0; rf < 2; ++rf)
        #pragma unroll
        for (int r = 0; r < 4; ++r)
            thrv[rf][r] = fdec(dotmax[rowbase + rf * 16 + hi * 4 + r]) - M;

    const int chunk0 = blockIdx.x * 64;
    const int sb = wave * 2048 + lane * 16;

    #pragma unroll
    for (int p = 0; p < 2; ++p) {
        const char* src = cbytes + (size_t)(chunk0 + p) * 8192 + sb;
        char*       dst = &Bt[p][sb];
        gll16(src, dst);
        gll16(src + 1024, dst + 1024);
    }

    for (int t = 0; t < 64; ++t) {
        asm volatile("s_waitcnt vmcnt(2)" ::: "memory");
        __builtin_amdgcn_sched_barrier(0);
        __builtin_amdgcn_s_barrier();
        __builtin_amdgcn_sched_barrier(0);
        {
            int st_t = (t + 2 <= 63) ? (t + 2) : 63;
            const char* src = cbytes + (size_t)(chunk0 + st_t) * 8192 + sb;
            char*       dst = &Bt[(t + 2) % 3][sb];
            gll16(src, dst);
            gll16(src + 1024, dst + 1024);
        }
        const char* bt = Bt[t % 3];
        f32x4 acc[2];
        acc[0] = (f32x4){0.f, 0.f, 0.f, 0.f};
        acc[1] = (f32x4){0.f, 0.f, 0.f, 0.f};
        __builtin_amdgcn_s_setprio(1);
        #pragma unroll
        for (int ks = 0; ks < 8; ++ks) {
            v8h b0 = *(const v8h*)(bt + (size_t)ks * 1024 + lane * 16);
            acc[0] = __builtin_amdgcn_mfma_f32_16x16x32_f16(a[0][ks], b0, acc[0], 0, 0, 0);
            acc[1] = __builtin_amdgcn_mfma_f32_16x16x32_f16(a[1][ks], b0, acc[1], 0, 0, 0);
        }
        __builtin_amdgcn_s_setprio(0);
        bool hit = false;
        #pragma unroll
        for (int rf = 0; rf < 2; ++rf)
            #pragma unroll
            for (int r = 0; r < 4; ++r)
                hit = hit || (acc[rf][r] >= thrv[rf][r]);
        if (__any(hit)) {
            #pragma unroll
            for (int rf = 0; rf < 2; ++rf)
                #pragma unroll
                for (int r = 0; r < 4; ++r)
                    if (acc[rf][r] >= thrv[rf][r]) {
                        int row = rowbase + rf * 16 + hi * 4 + r;
                        int col = (chunk0 + t) * 16 + (lane & 15);
                        unsigned pos = atomicAdd(&cnt[row], 1u);
                        if (pos < (unsigned)CAP2)
                            cand[(size_t)row * CAP2 + pos] = (unsigned)col;
                    }
        }
    }
}

// ===========================================================================
// Two-pass fallback GEMM (r8-proven barrier shape, rf=2) — untouched.
template <int COLLECT, int CAPN>
__global__ __attribute__((amdgpu_flat_work_group_size(256, 256), amdgpu_waves_per_eu(1, 4)))
void vq_gemm(const v8h* __restrict__ zhf, const char* __restrict__ cbytes,
             unsigned* __restrict__ dotmax, const unsigned* __restrict__ scal,
             unsigned* __restrict__ cnt, unsigned* __restrict__ cand) {
    __shared__ __align__(16) char Bt[3][8192];
    const int tid  = threadIdx.x;
    const int wave = tid >> 6, lane = tid & 63;
    const int rowbase = blockIdx.y * 128 + wave * 32;
    const int hi = (lane >> 4) & 3;

    v8h a[2][8];
    const int g16b = rowbase >> 4;
    #pragma unroll
    for (int rf = 0; rf < 2; ++rf)
        #pragma unroll
        for (int ks = 0; ks < 8; ++ks)
            a[rf][ks] = zhf[(size_t)((g16b + rf) * 8 + ks) * 64 + lane];

    float thrv[2][4];
    if (COLLECT) {
        float M = ((const float*)scal)[2];
        #pragma unroll
        for (int rf = 0; rf < 2; ++rf)
            #pragma unroll
            for (int r = 0; r < 4; ++r)
                thrv[rf][r] = fdec(dotmax[rowbase + rf * 16 + hi * 4 + r]) - M;
    }
    float runm[2][4];
    if (!COLLECT) {
        #pragma unroll
        for (int rf = 0; rf < 2; ++rf)
            #pragma unroll
            for (int r = 0; r < 4; ++r) runm[rf][r] = -1e30f;
    }

    const int chunk0 = blockIdx.x * 64;
    const int sb = wave * 2048 + lane * 16;

    #pragma unroll
    for (int p = 0; p < 2; ++p) {
        const char* src = cbytes + (size_t)(chunk0 + p) * 8192 + sb;
        char*       dst = &Bt[p][sb];
        gll16(src, dst);
        gll16(src + 1024, dst + 1024);
    }

    for (int t = 0; t < 64; ++t) {
        asm volatile("s_waitcnt vmcnt(2)" ::: "memory");
        __builtin_amdgcn_sched_barrier(0);
        __builtin_amdgcn_s_barrier();
        __builtin_amdgcn_sched_barrier(0);
        {
            int st_t = (t + 2 <= 63) ? (t + 2) : 63;
            const char* src = cbytes + (size_t)(chunk0 + st_t) * 8192 + sb;
            char*       dst = &Bt[(t + 2) % 3][sb];
            gll16(src, dst);
            gll16(src + 1024, dst + 1024);
        }
        const char* bt = Bt[t % 3];
        f32x4 acc[2];
        acc[0] = (f32x4){0.f, 0.f, 0.f, 0.f};
        acc[1] = (f32x4){0.f, 0.f, 0.f, 0.f};
        #pragma unroll
        for (int ks = 0; ks < 8; ++ks) {
            v8h b0 = *(const v8h*)(bt + (size_t)ks * 1024 + lane * 16);
            acc[0] = __builtin_amdgcn_mfma_f32_16x16x32_f16(a[0][ks], b0, acc[0], 0, 0, 0);
            acc[1] = __builtin_amdgcn_mfma_f32_16x16x32_f16(a[1][ks], b0, acc[1], 0, 0, 0);
        }
        if (!COLLECT) {
            #pragma unroll
            for (int rf = 0; rf < 2; ++rf)
                #pragma unroll
                for (int r = 0; r < 4; ++r)
                    runm[rf][r] = fmaxf(runm[rf][r], acc[rf][r]);
        } else {
            bool hit = false;
            #pragma unroll
            for (int rf = 0; rf < 2; ++rf)
                #pragma unroll
                for (int r = 0; r < 4; ++r)
                    hit = hit || (acc[rf][r] >= thrv[rf][r]);
            if (__any(hit)) {
                #pragma unroll
                for (int rf = 0; rf < 2; ++rf)
                    #pragma unroll
                    for (int r = 0; r < 4; ++r)
                        if (acc[rf][r] >= thrv[rf][r]) {
                            int row = rowbase + rf * 16 + hi * 4 + r;
                            int col = (chunk0 + t) * 16 + (lane & 15);
                            unsigned pos = atomicAdd(&cnt[row], 1u);
                            if (pos < (unsigned)CAPN)
                                cand[(size_t)row * CAPN + pos] = (unsigned)col;
                        }
            }
        }
    }

    if (!COLLECT) {
        #pragma unroll
        for (int rf = 0; rf < 2; ++rf)
            #pragma unroll
            for (int r = 0; r < 4; ++r) {
                float v = runm[rf][r];
                v = fmaxf(v, __shfl_xor(v, 1, 64));
                v = fmaxf(v, __shfl_xor(v, 2, 64));
                v = fmaxf(v, __shfl_xor(v, 4, 64));
                v = fmaxf(v, __shfl_xor(v, 8, 64));
                if ((lane & 15) == 0)
                    atomicMax(&dotmax[rowbase + rf * 16 + hi * 4 + r], fkey(v));
            }
    }
}

// ===========================================================================
// Exact finish (r14-proven exact config: one row per 64-thread block).
// fp64 re-eval of candidates, lexmin (fl32 d, m); overflow/empty -> full scan.
template <int C>
__global__ void vq_finish(const float* __restrict__ zt, const float* __restrict__ cb,
                          const float* __restrict__ zs32,
                          const unsigned* __restrict__ cnt, const unsigned* __restrict__ cand,
                          float* __restrict__ outq, float* __restrict__ outi) {
    const int row  = blockIdx.x;
    const int lane = threadIdx.x;                   // 64
    const unsigned nc = cnt[row];
    const double zs = (double)zs32[row];
    float bd = __builtin_huge_valf();
    int   bi = 0x7fffffff;

    if (nc >= 1u && nc <= (unsigned)C) {
        const float4 zv = *(const float4*)(zt + (size_t)row * DIM + lane * 4);
        for (unsigned i = 0; i < nc; ++i) {
            int m = (int)cand[(size_t)row * C + i];
            const float4 ev = *(const float4*)(cb + (size_t)m * DIM + lane * 4);
            double s = (double)zv.x * (double)ev.x + (double)zv.y * (double)ev.y
                     + (double)zv.z * (double)ev.z + (double)zv.w * (double)ev.w;
            #pragma unroll
            for (int off = 1; off < 64; off <<= 1) s += __shfl_xor(s, off, 64);
            float d = (float)(zs - 2.0 * s);
            if (d < bd || (d == bd && m < bi)) { bd = d; bi = m; }
        }
    } else {
        const float4* zr4 = (const float4*)(zt + (size_t)row * DIM);
        float lbd = __builtin_huge_valf();
        int   lbi = 0x7fffffff;
        for (int rep = 0; rep < NCODES / 64; ++rep) {
            int m = rep * 64 + lane;
            const float4* er4 = (const float4*)(cb + (size_t)m * DIM);
            double s0 = 0.0, s1 = 0.0;
            #pragma unroll 4
            for (int c4 = 0; c4 < DIM / 8; ++c4) {
                float4 z4 = zr4[c4], e4 = er4[c4];
                float4 z5 = zr4[c4 + 32], e5 = er4[c4 + 32];
                s0 += (double)z4.x * (double)e4.x + (double)z4.y * (double)e4.y
                    + (double)z4.z * (double)e4.z + (double)z4.w * (double)e4.w;
                s1 += (double)z5.x * (double)e5.x + (double)z5.y * (double)e5.y
                    + (double)z5.z * (double)e5.z + (double)z5.w * (double)e5.w;
            }
            double s = s0 + s1;
            float d = (float)(zs - 2.0 * s);
            if (d < lbd || (d == lbd && m < lbi)) { lbd = d; lbi = m; }
        }
        #pragma unroll
        for (int off = 1; off < 64; off <<= 1) {
            float od = __shfl_xor(lbd, off, 64);
            int   oi = __shfl_xor(lbi, off, 64);
            if (od < lbd || (od == lbd && oi < lbi)) { lbd = od; lbi = oi; }
        }
        bd = lbd; bi = lbi;
    }

    if (lane == 0) outi[row] = (float)bi;
    float4 v = *(const float4*)(cb + (size_t)bi * DIM + lane * 4);
    *(float4*)(outq + (size_t)row * DIM + lane * 4) = v;
}

// ===========================================================================
// Round-2 proven fallback path (only if ws is too small for both fast paths).
__global__ void vq_zsum32(const float* __restrict__ z, float* __restrict__ zs) {
    int n = blockIdx.x * 64 + threadIdx.x;
    int b = n >> 10, hw = n & 1023;
    const float* p = z + (size_t)b * (DIM * 1024) + hw;
    float h[2];
    #pragma unroll
    for (int half = 0; half < 2; ++half) {
        const float* q = p + (size_t)(half * 128) * 1024;
        float r[8];
        #pragma unroll
        for (int j = 0; j < 8; ++j) { float v = q[(size_t)j * 1024]; r[j] = __fmul_rn(v, v); }
        for (int i = 8; i < 128; i += 8)
            #pragma unroll
            for (int j = 0; j < 8; ++j) {
                float v = q[(size_t)(i + j) * 1024];
                r[j] = __fadd_rn(r[j], __fmul_rn(v, v));
            }
        float s01 = __fadd_rn(r[0], r[1]), s23 = __fadd_rn(r[2], r[3]);
        float s45 = __fadd_rn(r[4], r[5]), s67 = __fadd_rn(r[6], r[7]);
        h[half] = __fadd_rn(__fadd_rn(s01, s23), __fadd_rn(s45, s67));
    }
    zs[n] = __fadd_rn(h[0], h[1]);
}

__global__ __launch_bounds__(256, 2)
void vq_main(const float* __restrict__ z, const float* __restrict__ cb,
             const float* __restrict__ zs32, int* __restrict__ outidx) {
    __shared__ __align__(16) float ztl[32][260];
    __shared__ __align__(16) float et[16][260];
    const int tid = threadIdx.x;
    const int n0 = blockIdx.x * 32;
    const int b = n0 >> 10, hw0 = n0 & 1023;
    const float* zb = z + (size_t)b * (DIM * 1024) + hw0;
    for (int i = tid; i < 32 * DIM; i += 256) {
        int r = i & 31, c = i >> 5;
        ztl[r][c] = zb[(size_t)c * 1024 + r];
    }
    const int cg = tid & 15, rg = tid >> 4;
    const int r0 = rg * 2, r1 = r0 + 1;
    const float zsa = zs32[n0 + r0], zsb = zs32[n0 + r1];
    float b0d = __builtin_huge_valf(), b1d = __builtin_huge_valf();
    int b0i = 0, b1i = 0;
    for (int m0 = 0; m0 < NCODES; m0 += 16) {
        __syncthreads();
        for (int i = tid; i < 16 * 64; i += 256) {
            int m = i >> 6, q = i & 63;
            float4 v = *(const float4*)(cb + (size_t)(m0 + m) * DIM + q * 4);
            *(float4*)&et[m][q * 4] = v;
        }
        __syncthreads();
        double a0 = 0.0, a1 = 0.0;
        #pragma unroll 8
        for (int k4 = 0; k4 < DIM / 4; ++k4) {
            float4 ev = *(const float4*)&et[cg][k4 * 4];
            float4 z0 = *(const float4*)&ztl[r0][k4 * 4];
            float4 z1 = *(const float4*)&ztl[r1][k4 * 4];
            double e0 = ev.x, e1 = ev.y, e2 = ev.z, e3 = ev.w;
            a0 += (double)z0.x * e0; a1 += (double)z1.x * e0;
            a0 += (double)z0.y * e1; a1 += (double)z1.y * e1;
            a0 += (double)z0.z * e2; a1 += (double)z1.z * e2;
            a0 += (double)z0.w * e3; a1 += (double)z1.w * e3;
        }
        const int m = m0 + cg;
        float d0 = (float)((double)zsa - 2.0 * a0);
        float d1 = (float)((double)zsb - 2.0 * a1);
        if (d0 < b0d) { b0d = d0; b0i = m; }
        if (d1 < b1d) { b1d = d1; b1i = m; }
    }
    #pragma unroll
    for (int off = 1; off < 16; off <<= 1) {
        float od0 = __shfl_xor(b0d, off, 64); int oi0 = __shfl_xor(b0i, off, 64);
        if (od0 < b0d || (od0 == b0d && oi0 < b0i)) { b0d = od0; b0i = oi0; }
        float od1 = __shfl_xor(b1d, off, 64); int oi1 = __shfl_xor(b1i, off, 64);
        if (od1 < b1d || (od1 == b1d && oi1 < b1i)) { b1d = od1; b1i = oi1; }
    }
    if (cg == 0) { outidx[n0 + r0] = b0i; outidx[n0 + r1] = b1i; }
}

__global__ void vq_gather(const float* __restrict__ cb, const int* __restrict__ idx,
                          float* __restrict__ outq, float* __restrict__ outi) {
    int n = blockIdx.x, t = threadIdx.x;
    int m = idx[n];
    float4 v = *(const float4*)(cb + (size_t)m * DIM + t * 4);
    *(float4*)(outq + (size_t)n * DIM + t * 4) = v;
    if (t == 0) outi[n] = (float)m;
}

// ===========================================================================
extern "C" void kernel_launch(void* const* d_in, const int* in_sizes, int n_in,
                              void* d_out, int out_size, void* d_ws, size_t ws_size,
                              hipStream_t stream) {
    const float* z  = (const float*)d_in[0];
    const float* cb = (const float*)d_in[1];
    float* outq = (float*)d_out;
    float* outi = outq + (size_t)NROWS * DIM;
    char* ws = (char*)d_ws;

    if (ws_size >= NWS_NEEDED) {
        // ---- seeded path: merged prep, margin kernel, rf=2 seed+collect ----
        float*     zt     = (float*)(ws + NWS_ZT);
        _Float16*  zhf    = (_Float16*)(ws + NWS_ZHF);
        _Float16*  chf    = (_Float16*)(ws + NWS_CHF);
        float*     zs32   = (float*)(ws + NWS_ZS);
        unsigned*  dotmax = (unsigned*)(ws + NWS_DOTMAX);
        unsigned*  cnt    = (unsigned*)(ws + NWS_CNT);
        unsigned*  scal   = (unsigned*)(ws + NWS_SCAL);
        unsigned*  cand   = (unsigned*)(ws + NWS_CAND);

        // dotmax(64K) + cnt(64K) + scal(256B) contiguous: one memset
        hipMemsetAsync(dotmax, 0, 65536 + 65536 + 256, stream);

        vq_prep    <<<512, 64, 0, stream>>>(z, zt, zs32, zhf, cb, chf, scal);
        vq_margin  <<<1, 1, 0, stream>>>(scal);
        vq_seed    <<<dim3(16, 128), 256, 0, stream>>>((const v8h*)zhf, (const char*)chf,
                                                       dotmax);
        vq_collect <<<dim3(16, 128), 256, 0, stream>>>((const v8h*)zhf, (const char*)chf,
                                                       dotmax, scal, cnt, cand);
        vq_finish<CAP2><<<NROWS, 64, 0, stream>>>(zt, cb, zs32, cnt, cand, outq, outi);
    } else if (ws_size >= WS_NEEDED) {
        // -------- r8-proven two-pass path --------
        float*     zt     = (float*)(ws + WS_ZT);
        _Float16*  zhf    = (_Float16*)(ws + WS_ZHF);
        _Float16*  chf    = (_Float16*)(ws + WS_CHF);
        float*     zs32   = (float*)(ws + WS_ZS);
        unsigned*  dotmax = (unsigned*)(ws + WS_DOTMAX);
        unsigned*  cnt    = (unsigned*)(ws + WS_CNT);
        unsigned*  cand   = (unsigned*)(ws + WS_CAND);
        unsigned*  scal   = (unsigned*)(ws + WS_SCAL);

        hipMemsetAsync(dotmax, 0, 65536, stream);
        hipMemsetAsync(cnt,    0, 65536, stream);
        hipMemsetAsync(scal,   0, 256,   stream);

        vq_prep    <<<512, 64, 0, stream>>>(z, zt, zs32, zhf, cb, chf, scal);
        vq_margin  <<<1, 1, 0, stream>>>(scal);
        vq_gemm<0, CAP><<<dim3(16, 128), 256, 0, stream>>>((const v8h*)zhf, (const char*)chf,
                                                           dotmax, scal, cnt, cand);
        vq_gemm<1, CAP><<<dim3(16, 128), 256, 0, stream>>>((const v8h*)zhf, (const char*)chf,
                                                           dotmax, scal, cnt, cand);
        vq_finish<CAP><<<NROWS, 64, 0, stream>>>(zt, cb, zs32, cnt, cand, outq, outi);
    } else {
        float* zs32 = (float*)d_ws;
        int*   idx  = (int*)(zs32 + NROWS);
        vq_zsum32<<<NROWS / 64, 64, 0, stream>>>(z, zs32);
        vq_main  <<<NROWS / 32, 256, 0, stream>>>(z, cb, zs32, idx);
        vq_gather<<<NROWS, 64, 0, stream>>>(cb, idx, outq, outi);
    }
}